// Round 2
// baseline (15202.292 us; speedup 1.0000x reference)
//
#include <hip/hip_runtime.h>
#include <hip/hip_cooperative_groups.h>

namespace cg = cooperative_groups;

#define NB    256
#define NT    1024
#define BATCH 32
#define TENC  1024
#define HD    1024
#define ED    128
#define LL    128
#define GD    4096
#define IND   1152
#define NCHUNK 64
#define PSTR   520   // floats per partial chunk: 1024 bf16 (512 fl) + m + s + pad

// ws float offsets
#define HBUF_OFF 131072                              // base: [0, 131072)
#define PART_OFF (HBUF_OFF + 4*BATCH*HD)             // h ring[4]
#define CTXC_OFF (PART_OFF + 2*BATCH*NCHUNK*PSTR)    // partials ring[2]
#define LG_OFF   (CTXC_OFF + 2*BATCH*HD)             // combined ctx ring[2]
#define CTXB_OFF (LG_OFF + 2*BATCH*ED)               // logits ring[2]
#define WS_NEED_BF16 ((size_t)CTXB_OFF + (size_t)BATCH*TENC*HD/2)  // floats

__device__ __forceinline__ float sigf(float x) {
  return __builtin_amdgcn_rcpf(1.0f + __expf(-x));
}
__device__ __forceinline__ float tanhf_fast(float x) {
  return 1.0f - 2.0f * __builtin_amdgcn_rcpf(1.0f + __expf(2.0f * x));
}
__device__ __forceinline__ float dot4(const float4& a, const float4& b) {
  return a.x*b.x + a.y*b.y + a.z*b.z + a.w*b.w;
}
__device__ __forceinline__ void fma4a(float4& acc, const float4& a, const float4& b) {
  acc.x = fmaf(a.x, b.x, acc.x); acc.y = fmaf(a.y, b.y, acc.y);
  acc.z = fmaf(a.z, b.z, acc.z); acc.w = fmaf(a.w, b.w, acc.w);
}
__device__ __forceinline__ void fma4(float4& a, float p, const float4& c) {
  a.x = fmaf(p, c.x, a.x); a.y = fmaf(p, c.y, a.y);
  a.z = fmaf(p, c.z, a.z); a.w = fmaf(p, c.w, a.w);
}
__device__ __forceinline__ void mul4(float4& a, float s) { a.x*=s; a.y*=s; a.z*=s; a.w*=s; }
__device__ __forceinline__ unsigned bfrne(float f) {       // f32 -> bf16 RNE
  unsigned v = __float_as_uint(f);
  return (v + 0x7fffu + ((v >> 16) & 1u)) >> 16;
}
__device__ __forceinline__ uint4 pack8(const float4& a, const float4& b) {
  uint4 r;
  r.x = bfrne(a.x) | (bfrne(a.y) << 16);
  r.y = bfrne(a.z) | (bfrne(a.w) << 16);
  r.z = bfrne(b.x) | (bfrne(b.y) << 16);
  r.w = bfrne(b.z) | (bfrne(b.w) << 16);
  return r;
}
__device__ __forceinline__ float bflo(unsigned u) { return __uint_as_float(u << 16); }
__device__ __forceinline__ float bfhi(unsigned u) { return __uint_as_float(u & 0xffff0000u); }

// base[b][g] = b_ih[g] + b_hh[g] + dot(ctx0[b], W_ih[g][E:])  (time-invariant)
__global__ __launch_bounds__(256) void base_kernel(
    const float* __restrict__ ctxt, const float* __restrict__ Wih,
    const float* __restrict__ bih, const float* __restrict__ bhh,
    float* __restrict__ base) {
  int id = blockIdx.x * 256 + threadIdx.x;
  int b = id & (BATCH - 1);
  int g = id >> 5;
  const float4* c4 = reinterpret_cast<const float4*>(ctxt + (size_t)b * TENC * HD);
  const float4* w4 = reinterpret_cast<const float4*>(Wih + (size_t)g * IND + ED);
  float4 acc = make_float4(0,0,0,0);
#pragma unroll 8
  for (int kk = 0; kk < HD/4; ++kk) fma4a(acc, c4[kk], w4[kk]);
  base[(size_t)b * GD + g] = bih[g] + bhh[g] + acc.x + acc.y + acc.z + acc.w;
}

// context f32 -> bf16 (RNE), 8 elements/thread
__global__ __launch_bounds__(256) void cvt_kernel(
    const float* __restrict__ src, unsigned short* __restrict__ dst) {
  size_t i = ((size_t)blockIdx.x * 256 + threadIdx.x) * 8;
  float4 a = *reinterpret_cast<const float4*>(src + i);
  float4 b = *reinterpret_cast<const float4*>(src + i + 4);
  *reinterpret_cast<uint4*>(dst + i) = pack8(a, b);
}

// Persistent cooperative kernel, 1 grid.sync per step.
// waves 0-7 (tid<512): gates(k) -> lds -> (tid<128) cell -> h_k
// waves 8-15: attn partials(k-1); combine-slice(k-2); logits(k-3); lsm(k-4)
template<bool BF16C>
__global__ __launch_bounds__(NT, 4) void decoder_kernel(
    const float* __restrict__ ctxt, const float* __restrict__ gt,
    const float* __restrict__ Wih, const float* __restrict__ Whh,
    const float* __restrict__ Wout, const float* __restrict__ bout,
    float* __restrict__ ws, float* __restrict__ out) {
  cg::grid_group grid = cg::this_grid();
  const int blk = blockIdx.x;
  const int tid = threadIdx.x;
  const int lane = tid & 63;

  float* base  = ws;
  float* hbuf  = ws + HBUF_OFF;
  float* part  = ws + PART_OFF;
  float* ctxc  = ws + CTXC_OFF;
  float* lgbuf = ws + LG_OFF;
  const unsigned short* ctxb = reinterpret_cast<const unsigned short*>(ws + CTXB_OFF);

  __shared__ float glds[512];

  // gates mapping (tid < 512): one gate row per thread
  const int gb   = tid & 31;
  const int gr   = (tid >> 5) & 3;
  const int gj   = blk * 4 + (tid >> 7);
  const int grow = gr * HD + gj;
  // cell mapping (tid < 128)
  const int cb = tid & 31, cj = blk * 4 + (tid >> 5);
  float c_reg = 0.0f;

  // attn mapping (tid >= 512)
  const int ab    = blk >> 3;
  const int asub  = blk & 7;
  const int aw    = (tid >> 6) - 8;      // 0..7
  const int chunk = asub * 8 + aw;       // 0..63
  const int pos0  = chunk * 16;

  for (int k = 0; k <= 131; ++k) {
    if (tid < 512) {
      if (k <= LL - 1) {
        const float4* h4 = reinterpret_cast<const float4*>(hbuf + (size_t)((k+3)&3)*(BATCH*HD) + (size_t)gb*HD);
        const float4* w4 = reinterpret_cast<const float4*>(Whh + (size_t)grow * HD);
        float4 acc0 = make_float4(0,0,0,0), acc1 = acc0;
#pragma unroll 8
        for (int kk = 0; kk < HD/4; kk += 2) {
          fma4a(acc0, h4[kk],   w4[kk]);
          fma4a(acc1, h4[kk+1], w4[kk+1]);
        }
        float a = base[(size_t)gb * GD + grow];
        if (k == 0) {
          a += Wih[(size_t)grow * IND];   // word_0 = onehot(0)
        } else {
          const float4* wd = reinterpret_cast<const float4*>(gt + ((size_t)gb*LL + (k-1))*ED);
          const float4* wi = reinterpret_cast<const float4*>(Wih + (size_t)grow * IND);
#pragma unroll
          for (int kk = 0; kk < ED/4; ++kk) fma4a(acc0, wd[kk], wi[kk]);
        }
        a += acc0.x + acc0.y + acc0.z + acc0.w + acc1.x + acc1.y + acc1.z + acc1.w;
        glds[gr * 128 + (tid >> 7) * 32 + gb] = a;
      }
    } else {
      // ---- attention partials for t1 = k-1 (16 positions per wave) ----
      if (k >= 1 && k <= LL) {
        const int t1 = k - 1;
        const float4* h4 = reinterpret_cast<const float4*>(hbuf + (size_t)(t1&3)*(BATCH*HD) + (size_t)ab*HD);
        float4 hA0 = h4[2*lane], hA1 = h4[2*lane+1];
        float4 hB0 = h4[128+2*lane], hB1 = h4[128+2*lane+1];
        float m = -3.0e38f, s = 0.0f;
        float4 aA0 = make_float4(0,0,0,0), aA1 = aA0, aB0 = aA0, aB1 = aA0;
        const uint4* cr4 = nullptr;
        const float4* cf4 = nullptr;
        uint4 n0, n1;
        float4 f0, f1, f2, f3;
        if constexpr (BF16C) {
          cr4 = reinterpret_cast<const uint4*>(ctxb + ((size_t)ab*TENC + pos0)*HD);
          n0 = cr4[lane]; n1 = cr4[64 + lane];
        } else {
          cf4 = reinterpret_cast<const float4*>(ctxt + ((size_t)ab*TENC + pos0)*HD);
          f0 = cf4[2*lane]; f1 = cf4[2*lane+1]; f2 = cf4[128+2*lane]; f3 = cf4[128+2*lane+1];
        }
        for (int p = 0; p < 16; ++p) {
          float4 cA0, cA1, cB0, cB1;
          if constexpr (BF16C) {
            uint4 u0 = n0, u1 = n1;
            if (p < 15) { n0 = cr4[(p+1)*128 + lane]; n1 = cr4[(p+1)*128 + 64 + lane]; }
            cA0 = make_float4(bflo(u0.x), bfhi(u0.x), bflo(u0.y), bfhi(u0.y));
            cA1 = make_float4(bflo(u0.z), bfhi(u0.z), bflo(u0.w), bfhi(u0.w));
            cB0 = make_float4(bflo(u1.x), bfhi(u1.x), bflo(u1.y), bfhi(u1.y));
            cB1 = make_float4(bflo(u1.z), bfhi(u1.z), bflo(u1.w), bfhi(u1.w));
          } else {
            cA0 = f0; cA1 = f1; cB0 = f2; cB1 = f3;
            if (p < 15) {
              f0 = cf4[(p+1)*256 + 2*lane];       f1 = cf4[(p+1)*256 + 2*lane+1];
              f2 = cf4[(p+1)*256 + 128 + 2*lane]; f3 = cf4[(p+1)*256 + 128 + 2*lane+1];
            }
          }
          float4 dv = make_float4(0,0,0,0);
          fma4a(dv, cA0, hA0); fma4a(dv, cA1, hA1);
          fma4a(dv, cB0, hB0); fma4a(dv, cB1, hB1);
          float d = dv.x + dv.y + dv.z + dv.w;
#pragma unroll
          for (int o = 32; o > 0; o >>= 1) d += __shfl_xor(d, o);
          float mn = fmaxf(m, d);
          if (mn > m) {            // wave-uniform
            float sc = __expf(m - mn);
            s *= sc; mul4(aA0, sc); mul4(aA1, sc); mul4(aB0, sc); mul4(aB1, sc);
            m = mn;
          }
          float pw = __expf(d - m);
          s += pw;
          fma4(aA0, pw, cA0); fma4(aA1, pw, cA1);
          fma4(aB0, pw, cB0); fma4(aB1, pw, cB1);
        }
        float* pb = part + ((size_t)((t1&1)*BATCH + ab)*NCHUNK + chunk) * PSTR;
        uint4* pu = reinterpret_cast<uint4*>(pb);
        pu[lane]      = pack8(aA0, aA1);
        pu[64 + lane] = pack8(aB0, aB1);
        if (lane == 0) { pb[512] = m; pb[513] = s; }
      }
      // ---- combine slice for t2 = k-2 (waves 8,9: 128 elements/block) ----
      if (k >= 2 && k <= LL + 1) {
        const int tid2 = tid - 512;
        if (tid2 < 128) {
          const int t2 = k - 2;
          const int e = asub * 128 + tid2;
          const float* pb0 = part + (size_t)((t2&1)*BATCH + ab) * NCHUNK * PSTR;
          float mc = pb0[(size_t)lane * PSTR + 512];
          float sc = pb0[(size_t)lane * PSTR + 513];
          float M = mc;
#pragma unroll
          for (int o = 32; o > 0; o >>= 1) M = fmaxf(M, __shfl_xor(M, o));
          float wl = __expf(mc - M);
          float S = wl * sc;
#pragma unroll
          for (int o = 32; o > 0; o >>= 1) S += __shfl_xor(S, o);
          const unsigned short* pu0 = reinterpret_cast<const unsigned short*>(pb0);
          float acc = 0.0f;
#pragma unroll 8
          for (int c = 0; c < NCHUNK; ++c) {
            float w = __shfl(wl, c);
            float v = bflo((unsigned)pu0[(size_t)c * (PSTR*2) + e]);
            acc = fmaf(w, v, acc);
          }
          ctxc[(size_t)(t2&1)*(BATCH*HD) + (size_t)ab*HD + e] = acc * __builtin_amdgcn_rcpf(S);
        }
      }
      // ---- logits for t3 = k-3 (2 per wave, 16 per block) ----
      if (k >= 3 && k <= LL + 2) {
        const int t3 = k - 3;
        const float4* hh = reinterpret_cast<const float4*>(hbuf + (size_t)(t3&3)*(BATCH*HD) + (size_t)ab*HD);
        const float4* cx = reinterpret_cast<const float4*>(ctxc + (size_t)(t3&1)*(BATCH*HD) + (size_t)ab*HD);
#pragma unroll
        for (int q = 0; q < 2; ++q) {
          const int e = asub * 16 + aw * 2 + q;
          const float4* wo = reinterpret_cast<const float4*>(Wout + (size_t)e * 2 * HD);
          float4 acc = make_float4(0,0,0,0);
#pragma unroll
          for (int jj = 0; jj < 4; ++jj) {
            fma4a(acc, hh[lane + 64*jj], wo[lane + 64*jj]);
            fma4a(acc, cx[lane + 64*jj], wo[256 + lane + 64*jj]);
          }
          float d = acc.x + acc.y + acc.z + acc.w;
#pragma unroll
          for (int o = 32; o > 0; o >>= 1) d += __shfl_xor(d, o);
          if (lane == 0)
            lgbuf[(size_t)(t3&1)*(BATCH*ED) + (size_t)ab*ED + e] = d + bout[e];
        }
      }
      // ---- log-softmax for t4 = k-4 (designated block, wave 8) ----
      if (asub == 0 && aw == 0 && k >= 4) {
        const int t4 = k - 4;
        const float* lg = lgbuf + (size_t)(t4&1)*(BATCH*ED) + (size_t)ab*ED;
        float v0 = lg[lane], v1 = lg[lane + 64];
        float mx = fmaxf(v0, v1);
#pragma unroll
        for (int o = 32; o > 0; o >>= 1) mx = fmaxf(mx, __shfl_xor(mx, o));
        float sm = __expf(v0 - mx) + __expf(v1 - mx);
#pragma unroll
        for (int o = 32; o > 0; o >>= 1) sm += __shfl_xor(sm, o);
        float lse = mx + __logf(sm);
        float* op = out + ((size_t)ab*LL + t4)*ED;
        op[lane]      = v0 - lse;
        op[lane + 64] = v1 - lse;
      }
    }
    __syncthreads();
    if (tid < 128 && k <= LL - 1) {
      float ig = sigf(glds[tid]);
      float fg = sigf(glds[128 + tid]);
      float gg = tanhf_fast(glds[256 + tid]);
      float og = sigf(glds[384 + tid]);
      c_reg = fg * c_reg + ig * gg;
      hbuf[(size_t)(k&3)*(BATCH*HD) + (size_t)cb*HD + cj] = og * tanhf_fast(c_reg);
    }
    grid.sync();
  }
}

extern "C" void kernel_launch(void* const* d_in, const int* in_sizes, int n_in,
                              void* d_out, int out_size, void* d_ws, size_t ws_size,
                              hipStream_t stream) {
  (void)in_sizes; (void)n_in; (void)out_size;
  const float* ctxt = (const float*)d_in[0];
  const float* gt   = (const float*)d_in[1];
  const float* Wih  = (const float*)d_in[2];
  const float* Whh  = (const float*)d_in[3];
  const float* bih  = (const float*)d_in[4];
  const float* bhh  = (const float*)d_in[5];
  const float* Wout = (const float*)d_in[6];
  const float* bout = (const float*)d_in[7];
  float* out = (float*)d_out;
  float* ws  = (float*)d_ws;

  const bool bf16c = (ws_size / sizeof(float)) >= WS_NEED_BF16;

  hipMemsetAsync(ws + HBUF_OFF, 0, (size_t)4*BATCH*HD*sizeof(float), stream);
  base_kernel<<<(BATCH*GD)/256, 256, 0, stream>>>(ctxt, Wih, bih, bhh, ws);

  if (bf16c) {
    cvt_kernel<<<(BATCH*TENC*HD/8)/256, 256, 0, stream>>>(
        ctxt, reinterpret_cast<unsigned short*>(ws + CTXB_OFF));
  }

  void* args[] = { (void*)&ctxt, (void*)&gt, (void*)&Wih, (void*)&Whh,
                   (void*)&Wout, (void*)&bout, (void*)&ws, (void*)&out };
  const void* kfun = bf16c ? reinterpret_cast<const void*>(&decoder_kernel<true>)
                           : reinterpret_cast<const void*>(&decoder_kernel<false>);
  hipLaunchCooperativeKernel(kfun, dim3(NB), dim3(NT), args, 0, stream);
}

// Round 3
// 12274.203 us; speedup vs baseline: 1.2386x; 1.2386x over previous
//
#include <hip/hip_runtime.h>
#include <hip/hip_cooperative_groups.h>

namespace cg = cooperative_groups;

#define NB    256
#define NT    1024
#define BATCH 32
#define TENC  1024
#define HD    1024
#define ED    128
#define LL    128
#define GD    4096
#define IND   1152
#define NCHUNK 64
#define PSTR   520   // floats per partial chunk: 1024 bf16 (512 fl) + m + s + pad

// ws float offsets
#define HBUF_OFF 131072                              // base: [0, 131072)
#define PART_OFF (HBUF_OFF + 4*BATCH*HD)             // h ring[4]
#define CTXC_OFF (PART_OFF + 2*BATCH*NCHUNK*PSTR)    // partials ring[2]
#define LG_OFF   (CTXC_OFF + 2*BATCH*HD)             // combined ctx ring[2]
#define CTXB_OFF (LG_OFF + 2*BATCH*ED)               // logits ring[2]
#define WS_NEED_BF16 ((size_t)CTXB_OFF + (size_t)BATCH*TENC*HD/2)  // floats

__device__ __forceinline__ float sigf(float x) {
  return __builtin_amdgcn_rcpf(1.0f + __expf(-x));
}
__device__ __forceinline__ float tanhf_fast(float x) {
  return 1.0f - 2.0f * __builtin_amdgcn_rcpf(1.0f + __expf(2.0f * x));
}
__device__ __forceinline__ void fma4a(float4& acc, const float4& a, const float4& b) {
  acc.x = fmaf(a.x, b.x, acc.x); acc.y = fmaf(a.y, b.y, acc.y);
  acc.z = fmaf(a.z, b.z, acc.z); acc.w = fmaf(a.w, b.w, acc.w);
}
__device__ __forceinline__ void fma4(float4& a, float p, const float4& c) {
  a.x = fmaf(p, c.x, a.x); a.y = fmaf(p, c.y, a.y);
  a.z = fmaf(p, c.z, a.z); a.w = fmaf(p, c.w, a.w);
}
__device__ __forceinline__ void mul4(float4& a, float s) { a.x*=s; a.y*=s; a.z*=s; a.w*=s; }
__device__ __forceinline__ unsigned bfrne(float f) {       // f32 -> bf16 RNE
  unsigned v = __float_as_uint(f);
  return (v + 0x7fffu + ((v >> 16) & 1u)) >> 16;
}
__device__ __forceinline__ uint4 pack8(const float4& a, const float4& b) {
  uint4 r;
  r.x = bfrne(a.x) | (bfrne(a.y) << 16);
  r.y = bfrne(a.z) | (bfrne(a.w) << 16);
  r.z = bfrne(b.x) | (bfrne(b.y) << 16);
  r.w = bfrne(b.z) | (bfrne(b.w) << 16);
  return r;
}
__device__ __forceinline__ float bflo(unsigned u) { return __uint_as_float(u << 16); }
__device__ __forceinline__ float bfhi(unsigned u) { return __uint_as_float(u & 0xffff0000u); }

// base[b][g] = b_ih[g] + b_hh[g] + dot(ctx0[b], W_ih[g][E:])  (time-invariant)
__global__ __launch_bounds__(256) void base_kernel(
    const float* __restrict__ ctxt, const float* __restrict__ Wih,
    const float* __restrict__ bih, const float* __restrict__ bhh,
    float* __restrict__ base) {
  int id = blockIdx.x * 256 + threadIdx.x;
  int b = id & (BATCH - 1);
  int g = id >> 5;
  const float4* c4 = reinterpret_cast<const float4*>(ctxt + (size_t)b * TENC * HD);
  const float4* w4 = reinterpret_cast<const float4*>(Wih + (size_t)g * IND + ED);
  float4 acc = make_float4(0,0,0,0);
#pragma unroll 8
  for (int kk = 0; kk < HD/4; ++kk) fma4a(acc, c4[kk], w4[kk]);
  base[(size_t)b * GD + g] = bih[g] + bhh[g] + acc.x + acc.y + acc.z + acc.w;
}

// context f32 -> bf16 (RNE), 8 elements/thread
__global__ __launch_bounds__(256) void cvt_kernel(
    const float* __restrict__ src, unsigned short* __restrict__ dst) {
  size_t i = ((size_t)blockIdx.x * 256 + threadIdx.x) * 8;
  float4 a = *reinterpret_cast<const float4*>(src + i);
  float4 b = *reinterpret_cast<const float4*>(src + i + 4);
  *reinterpret_cast<uint4*>(dst + i) = pack8(a, b);
}

// Persistent cooperative kernel, 1 grid.sync per step.
//   waves 0-3  : gates(k), K-split coalesced, Whh register-resident
//   waves 4-11 : attn partials(k-1), bf16 context, prefetch-2
//   waves 12-13: softmax combine(k-2)
//   waves 12-15: logits(k-3); wave 15 of asub==0: log-softmax(k-4)
//   tid<128    : cell(k) after __syncthreads
template<bool BF16C>
__global__ __launch_bounds__(NT, 4) void decoder_kernel(
    const float* __restrict__ ctxt, const float* __restrict__ gt,
    const float* __restrict__ Wih, const float* __restrict__ Whh,
    const float* __restrict__ Wout, const float* __restrict__ bout,
    float* __restrict__ ws, float* __restrict__ out) {
  cg::grid_group grid = cg::this_grid();
  const int blk = blockIdx.x;
  const int tid = threadIdx.x;
  const int lane = tid & 63;

  float* base  = ws;
  float* hbuf  = ws + HBUF_OFF;
  float* part  = ws + PART_OFF;
  float* ctxc  = ws + CTXC_OFF;
  float* lgbuf = ws + LG_OFF;
  const unsigned short* ctxb = reinterpret_cast<const unsigned short*>(ws + CTXB_OFF);

  __shared__ float glds[512];

  const int ab   = blk >> 3;
  const int asub = blk & 7;

  // ---- gate waves: preload time-invariant weights into registers ----
  float4 Wr[4][4];       // 4 gate rows x K-slice (lane covers k = 4*lane + 256*t)
  float2 Wi2r[4];        // word-part K-slice (lane covers k = 2*lane)
  float  c_reg = 0.0f;   // cell state (tid < 128)
  const int gw = tid >> 6;
  if (tid < 256) {
    const float4* Whh4 = reinterpret_cast<const float4*>(Whh);
    const float2* Wih2 = reinterpret_cast<const float2*>(Wih);
#pragma unroll
    for (int r = 0; r < 4; ++r) {
      const int grow = r * HD + blk * 4 + gw;
#pragma unroll
      for (int t = 0; t < 4; ++t)
        Wr[r][t] = Whh4[(size_t)grow * 256 + lane + 64 * t];
      Wi2r[r] = Wih2[(size_t)grow * 576 + lane];
    }
  }

  // attention mapping
  const int aw    = (tid >> 6) - 4;      // 0..7 for attn waves
  const int chunk = asub * 8 + aw;
  const int pos0  = chunk * 16;

  for (int k = 0; k <= 131; ++k) {
    if (tid < 256) {
      // ---- gates(k): 4 rows/wave, all 32 b, K split across 64 lanes ----
      if (k <= LL - 1) {
        const float* hrow = hbuf + (size_t)((k + 3) & 3) * (BATCH * HD);
        const float2* gt2 = reinterpret_cast<const float2*>(gt);
#pragma unroll 2
        for (int b = 0; b < BATCH; ++b) {
          const float4* h4 = reinterpret_cast<const float4*>(hrow + (size_t)b * HD);
          float4 h0 = h4[lane], h1 = h4[lane + 64], h2 = h4[lane + 128], h3 = h4[lane + 192];
          float2 wd;
          if (k == 0) { wd.x = (lane == 0) ? 1.0f : 0.0f; wd.y = 0.0f; }
          else        { wd = gt2[((size_t)b * LL + (k - 1)) * 64 + lane]; }
          float acc[4];
#pragma unroll
          for (int r = 0; r < 4; ++r) {
            float4 dv = make_float4(0,0,0,0);
            fma4a(dv, h0, Wr[r][0]); fma4a(dv, h1, Wr[r][1]);
            fma4a(dv, h2, Wr[r][2]); fma4a(dv, h3, Wr[r][3]);
            float a = dv.x + dv.y + dv.z + dv.w;
            a = fmaf(wd.x, Wi2r[r].x, a);
            a = fmaf(wd.y, Wi2r[r].y, a);
#pragma unroll
            for (int o = 32; o > 0; o >>= 1) a += __shfl_xor(a, o);
            acc[r] = a;
          }
          if (lane == 0) {
#pragma unroll
            for (int r = 0; r < 4; ++r)
              glds[r * 128 + gw * 32 + b] =
                  acc[r] + base[(size_t)b * GD + r * HD + blk * 4 + gw];
          }
        }
      }
    } else if (tid < 768) {
      // ---- attention partials for t1 = k-1 (16 positions/wave) ----
      if (k >= 1 && k <= LL) {
        const int t1 = k - 1;
        const float4* h4 = reinterpret_cast<const float4*>(
            hbuf + (size_t)(t1 & 3) * (BATCH * HD) + (size_t)ab * HD);
        float4 hA0 = h4[2*lane], hA1 = h4[2*lane+1];
        float4 hB0 = h4[128+2*lane], hB1 = h4[128+2*lane+1];
        float m = -3.0e38f, s = 0.0f;
        float4 aA0 = make_float4(0,0,0,0), aA1 = aA0, aB0 = aA0, aB1 = aA0;
        if constexpr (BF16C) {
          const uint4* cr4 = reinterpret_cast<const uint4*>(ctxb + ((size_t)ab*TENC + pos0)*HD);
          uint4 pa0 = cr4[lane],       pa1 = cr4[64 + lane];
          uint4 pb0 = cr4[128 + lane], pb1 = cr4[192 + lane];
          for (int p = 0; p < 16; ++p) {
            uint4 u0 = pa0, u1 = pa1;
            pa0 = pb0; pa1 = pb1;
            if (p < 14) { pb0 = cr4[(p+2)*128 + lane]; pb1 = cr4[(p+2)*128 + 64 + lane]; }
            float4 cA0 = make_float4(bflo(u0.x), bfhi(u0.x), bflo(u0.y), bfhi(u0.y));
            float4 cA1 = make_float4(bflo(u0.z), bfhi(u0.z), bflo(u0.w), bfhi(u0.w));
            float4 cB0 = make_float4(bflo(u1.x), bfhi(u1.x), bflo(u1.y), bfhi(u1.y));
            float4 cB1 = make_float4(bflo(u1.z), bfhi(u1.z), bflo(u1.w), bfhi(u1.w));
            float4 dv = make_float4(0,0,0,0);
            fma4a(dv, cA0, hA0); fma4a(dv, cA1, hA1);
            fma4a(dv, cB0, hB0); fma4a(dv, cB1, hB1);
            float d = dv.x + dv.y + dv.z + dv.w;
#pragma unroll
            for (int o = 32; o > 0; o >>= 1) d += __shfl_xor(d, o);
            float mn = fmaxf(m, d);
            if (mn > m) {            // wave-uniform
              float sc = __expf(m - mn);
              s *= sc; mul4(aA0, sc); mul4(aA1, sc); mul4(aB0, sc); mul4(aB1, sc);
              m = mn;
            }
            float pw = __expf(d - m);
            s += pw;
            fma4(aA0, pw, cA0); fma4(aA1, pw, cA1);
            fma4(aB0, pw, cB0); fma4(aB1, pw, cB1);
          }
          float* pb = part + ((size_t)((t1&1)*BATCH + ab)*NCHUNK + chunk) * PSTR;
          uint4* pu = reinterpret_cast<uint4*>(pb);
          pu[lane]      = pack8(aA0, aA1);
          pu[64 + lane] = pack8(aB0, aB1);
          if (lane == 0) { pb[512] = m; pb[513] = s; }
        } else {
          const float4* cf4 = reinterpret_cast<const float4*>(ctxt + ((size_t)ab*TENC + pos0)*HD);
          float4 f0 = cf4[2*lane], f1 = cf4[2*lane+1];
          float4 f2 = cf4[128+2*lane], f3 = cf4[128+2*lane+1];
          for (int p = 0; p < 16; ++p) {
            float4 cA0 = f0, cA1 = f1, cB0 = f2, cB1 = f3;
            if (p < 15) {
              f0 = cf4[(p+1)*256 + 2*lane];       f1 = cf4[(p+1)*256 + 2*lane+1];
              f2 = cf4[(p+1)*256 + 128 + 2*lane]; f3 = cf4[(p+1)*256 + 128 + 2*lane+1];
            }
            float4 dv = make_float4(0,0,0,0);
            fma4a(dv, cA0, hA0); fma4a(dv, cA1, hA1);
            fma4a(dv, cB0, hB0); fma4a(dv, cB1, hB1);
            float d = dv.x + dv.y + dv.z + dv.w;
#pragma unroll
            for (int o = 32; o > 0; o >>= 1) d += __shfl_xor(d, o);
            float mn = fmaxf(m, d);
            if (mn > m) {
              float sc = __expf(m - mn);
              s *= sc; mul4(aA0, sc); mul4(aA1, sc); mul4(aB0, sc); mul4(aB1, sc);
              m = mn;
            }
            float pw = __expf(d - m);
            s += pw;
            fma4(aA0, pw, cA0); fma4(aA1, pw, cA1);
            fma4(aB0, pw, cB0); fma4(aB1, pw, cB1);
          }
          float* pb = part + ((size_t)((t1&1)*BATCH + ab)*NCHUNK + chunk) * PSTR;
          uint4* pu = reinterpret_cast<uint4*>(pb);
          pu[lane]      = pack8(aA0, aA1);
          pu[64 + lane] = pack8(aB0, aB1);
          if (lane == 0) { pb[512] = m; pb[513] = s; }
        }
      }
    } else {
      // ---- combine slice for t2 = k-2 (waves 12-13) ----
      if (tid < 896 && k >= 2 && k <= LL + 1) {
        const int tid2 = tid - 768;        // 0..127
        const int t2 = k - 2;
        const int e = asub * 128 + tid2;
        const float* pb0 = part + (size_t)((t2&1)*BATCH + ab) * NCHUNK * PSTR;
        float mc = pb0[(size_t)lane * PSTR + 512];
        float sc = pb0[(size_t)lane * PSTR + 513];
        float M = mc;
#pragma unroll
        for (int o = 32; o > 0; o >>= 1) M = fmaxf(M, __shfl_xor(M, o));
        float wl = __expf(mc - M);
        float S = wl * sc;
#pragma unroll
        for (int o = 32; o > 0; o >>= 1) S += __shfl_xor(S, o);
        const unsigned short* pu0 = reinterpret_cast<const unsigned short*>(pb0);
        float acc = 0.0f;
#pragma unroll 8
        for (int c = 0; c < NCHUNK; ++c) {
          float w = __shfl(wl, c);
          float v = bflo((unsigned)pu0[(size_t)c * (PSTR*2) + e]);
          acc = fmaf(w, v, acc);
        }
        ctxc[(size_t)(t2&1)*(BATCH*HD) + (size_t)ab*HD + e] = acc * __builtin_amdgcn_rcpf(S);
      }
      // ---- logits for t3 = k-3 (waves 12-15, 4 e each) ----
      if (k >= 3 && k <= LL + 2) {
        const int t3 = k - 3;
        const int aw2 = (tid >> 6) - 12;   // 0..3
        const float4* hh = reinterpret_cast<const float4*>(
            hbuf + (size_t)(t3&3)*(BATCH*HD) + (size_t)ab*HD);
        const float4* cx = reinterpret_cast<const float4*>(
            ctxc + (size_t)(t3&1)*(BATCH*HD) + (size_t)ab*HD);
#pragma unroll
        for (int q = 0; q < 4; ++q) {
          const int e = asub * 16 + aw2 * 4 + q;
          const float4* wo = reinterpret_cast<const float4*>(Wout + (size_t)e * 2 * HD);
          float4 acc = make_float4(0,0,0,0);
#pragma unroll
          for (int jj = 0; jj < 4; ++jj) {
            fma4a(acc, hh[lane + 64*jj], wo[lane + 64*jj]);
            fma4a(acc, cx[lane + 64*jj], wo[256 + lane + 64*jj]);
          }
          float d = acc.x + acc.y + acc.z + acc.w;
#pragma unroll
          for (int o = 32; o > 0; o >>= 1) d += __shfl_xor(d, o);
          if (lane == 0)
            lgbuf[(size_t)(t3&1)*(BATCH*ED) + (size_t)ab*ED + e] = d + bout[e];
        }
      }
      // ---- log-softmax for t4 = k-4 (asub==0, wave 15) ----
      if (asub == 0 && tid >= 960 && k >= 4) {
        const int t4 = k - 4;
        const float* lg = lgbuf + (size_t)(t4&1)*(BATCH*ED) + (size_t)ab*ED;
        float v0 = lg[lane], v1 = lg[lane + 64];
        float mx = fmaxf(v0, v1);
#pragma unroll
        for (int o = 32; o > 0; o >>= 1) mx = fmaxf(mx, __shfl_xor(mx, o));
        float sm = __expf(v0 - mx) + __expf(v1 - mx);
#pragma unroll
        for (int o = 32; o > 0; o >>= 1) sm += __shfl_xor(sm, o);
        float lse = mx + __logf(sm);
        float* op = out + ((size_t)ab*LL + t4)*ED;
        op[lane]      = v0 - lse;
        op[lane + 64] = v1 - lse;
      }
    }
    __syncthreads();
    // ---- cell(k): 128 threads, one (b, j) unit each ----
    if (tid < 128 && k <= LL - 1) {
      const int cb = tid & 31, cw = tid >> 5;
      float ig = sigf(glds[cw*32 + cb]);
      float fg = sigf(glds[128 + cw*32 + cb]);
      float gg = tanhf_fast(glds[256 + cw*32 + cb]);
      float og = sigf(glds[384 + cw*32 + cb]);
      c_reg = fg * c_reg + ig * gg;
      hbuf[(size_t)(k&3)*(BATCH*HD) + (size_t)cb*HD + blk*4 + cw] = og * tanhf_fast(c_reg);
    }
    grid.sync();
  }
}

extern "C" void kernel_launch(void* const* d_in, const int* in_sizes, int n_in,
                              void* d_out, int out_size, void* d_ws, size_t ws_size,
                              hipStream_t stream) {
  (void)in_sizes; (void)n_in; (void)out_size;
  const float* ctxt = (const float*)d_in[0];
  const float* gt   = (const float*)d_in[1];
  const float* Wih  = (const float*)d_in[2];
  const float* Whh  = (const float*)d_in[3];
  const float* bih  = (const float*)d_in[4];
  const float* bhh  = (const float*)d_in[5];
  const float* Wout = (const float*)d_in[6];
  const float* bout = (const float*)d_in[7];
  float* out = (float*)d_out;
  float* ws  = (float*)d_ws;

  const bool bf16c = (ws_size / sizeof(float)) >= WS_NEED_BF16;

  hipMemsetAsync(ws + HBUF_OFF, 0, (size_t)4*BATCH*HD*sizeof(float), stream);
  base_kernel<<<(BATCH*GD)/256, 256, 0, stream>>>(ctxt, Wih, bih, bhh, ws);

  if (bf16c) {
    cvt_kernel<<<(BATCH*TENC*HD/8)/256, 256, 0, stream>>>(
        ctxt, reinterpret_cast<unsigned short*>(ws + CTXB_OFF));
  }

  void* args[] = { (void*)&ctxt, (void*)&gt, (void*)&Wih, (void*)&Whh,
                   (void*)&Wout, (void*)&bout, (void*)&ws, (void*)&out };
  const void* kfun = bf16c ? reinterpret_cast<const void*>(&decoder_kernel<true>)
                           : reinterpret_cast<const void*>(&decoder_kernel<false>);
  hipLaunchCooperativeKernel(kfun, dim3(NB), dim3(NT), args, 0, stream);
}

// Round 4
// 6975.145 us; speedup vs baseline: 2.1795x; 1.7597x over previous
//
#include <hip/hip_runtime.h>

#define NB    256
#define NT    1024
#define BATCH 32
#define TENC  1024
#define HD    1024
#define ED    128
#define LL    128
#define GD    4096
#define IND   1152
#define NCHUNK 64
#define PSTR   520   // floats per partial chunk: 1024 bf16 (512 fl) + m + s + pad

// ws float offsets
#define HBUF_OFF 131072                      // base: [0, 131072)
#define PART_OFF (HBUF_OFF + 131072)         // h ring[4]
#define CTXC_OFF (PART_OFF + 2129920)        // partials ring[2] (2*32*64*520)
#define LG_OFF   (CTXC_OFF + 65536)          // ctx ring[2]
#define CNT_OFF  (LG_OFF + 8192)             // logits ring[2]
#define CTXB_OFF (CNT_OFF + 64)              // barrier counter (padded)
#define WS_NEED_BF16 ((size_t)CTXB_OFF + (size_t)BATCH*TENC*HD/2)  // floats

__device__ __forceinline__ float sigf(float x) {
  return __builtin_amdgcn_rcpf(1.0f + __expf(-x));
}
__device__ __forceinline__ float tanhf_fast(float x) {
  return 1.0f - 2.0f * __builtin_amdgcn_rcpf(1.0f + __expf(2.0f * x));
}
__device__ __forceinline__ void fma4a(float4& acc, const float4& a, const float4& b) {
  acc.x = fmaf(a.x, b.x, acc.x); acc.y = fmaf(a.y, b.y, acc.y);
  acc.z = fmaf(a.z, b.z, acc.z); acc.w = fmaf(a.w, b.w, acc.w);
}
__device__ __forceinline__ void fma4(float4& a, float p, const float4& c) {
  a.x = fmaf(p, c.x, a.x); a.y = fmaf(p, c.y, a.y);
  a.z = fmaf(p, c.z, a.z); a.w = fmaf(p, c.w, a.w);
}
__device__ __forceinline__ void mul4(float4& a, float s) { a.x*=s; a.y*=s; a.z*=s; a.w*=s; }
__device__ __forceinline__ unsigned bfrne(float f) {       // f32 -> bf16 RNE
  unsigned v = __float_as_uint(f);
  return (v + 0x7fffu + ((v >> 16) & 1u)) >> 16;
}
__device__ __forceinline__ uint4 pack8(const float4& a, const float4& b) {
  uint4 r;
  r.x = bfrne(a.x) | (bfrne(a.y) << 16);
  r.y = bfrne(a.z) | (bfrne(a.w) << 16);
  r.z = bfrne(b.x) | (bfrne(b.y) << 16);
  r.w = bfrne(b.z) | (bfrne(b.w) << 16);
  return r;
}
__device__ __forceinline__ float bflo(unsigned u) { return __uint_as_float(u << 16); }
__device__ __forceinline__ float bfhi(unsigned u) { return __uint_as_float(u & 0xffff0000u); }

// ---- coherent (cross-XCD) access helpers: relaxed agent-scope atomics.
// These bypass stale L1/L2 and hit the device coherence point WITHOUT the
// L2 writeback/invalidate that cg::grid.sync's fences perform.
__device__ __forceinline__ float cldf(const float* p) {
  return __hip_atomic_load(p, __ATOMIC_RELAXED, __HIP_MEMORY_SCOPE_AGENT);
}
__device__ __forceinline__ void cstf(float* p, float v) {
  __hip_atomic_store(p, v, __ATOMIC_RELAXED, __HIP_MEMORY_SCOPE_AGENT);
}
__device__ __forceinline__ unsigned cld4(const void* p) {
  return __hip_atomic_load((const unsigned*)p, __ATOMIC_RELAXED, __HIP_MEMORY_SCOPE_AGENT);
}
__device__ __forceinline__ unsigned long long cld8(const void* p) {
  return __hip_atomic_load((const unsigned long long*)p, __ATOMIC_RELAXED, __HIP_MEMORY_SCOPE_AGENT);
}
__device__ __forceinline__ void cst8(void* p, unsigned long long v) {
  __hip_atomic_store((unsigned long long*)p, v, __ATOMIC_RELAXED, __HIP_MEMORY_SCOPE_AGENT);
}
__device__ __forceinline__ float4 ldc4(const float* p) {
  unsigned long long u0 = cld8(p), u1 = cld8(p + 2);
  return make_float4(__uint_as_float((unsigned)u0), __uint_as_float((unsigned)(u0 >> 32)),
                     __uint_as_float((unsigned)u1), __uint_as_float((unsigned)(u1 >> 32)));
}
__device__ __forceinline__ unsigned long long f2u(float a, float b) {
  return (unsigned long long)__float_as_uint(a) | ((unsigned long long)__float_as_uint(b) << 32);
}

// Grid barrier without cache-flushing fences. Safe because ALL cross-block
// RW data goes through coherent (agent-scope) loads/stores, and
// __syncthreads drains each wave's outstanding vmem before arrival.
__device__ __forceinline__ void gbar(unsigned* cnt, unsigned target) {
  __syncthreads();
  if (threadIdx.x == 0) {
    __hip_atomic_fetch_add(cnt, 1u, __ATOMIC_RELAXED, __HIP_MEMORY_SCOPE_AGENT);
    while (__hip_atomic_load(cnt, __ATOMIC_RELAXED, __HIP_MEMORY_SCOPE_AGENT) < target)
      __builtin_amdgcn_s_sleep(2);
  }
  __syncthreads();
}

// base[b][g] = b_ih[g] + b_hh[g] + dot(ctx0[b], W_ih[g][E:])  (time-invariant)
__global__ __launch_bounds__(256) void base_kernel(
    const float* __restrict__ ctxt, const float* __restrict__ Wih,
    const float* __restrict__ bih, const float* __restrict__ bhh,
    float* __restrict__ base) {
  int id = blockIdx.x * 256 + threadIdx.x;
  int b = id & (BATCH - 1);
  int g = id >> 5;
  const float4* c4 = reinterpret_cast<const float4*>(ctxt + (size_t)b * TENC * HD);
  const float4* w4 = reinterpret_cast<const float4*>(Wih + (size_t)g * IND + ED);
  float4 acc = make_float4(0,0,0,0);
#pragma unroll 8
  for (int kk = 0; kk < HD/4; ++kk) fma4a(acc, c4[kk], w4[kk]);
  base[(size_t)b * GD + g] = bih[g] + bhh[g] + acc.x + acc.y + acc.z + acc.w;
}

// context f32 -> bf16 (RNE), 8 elements/thread
__global__ __launch_bounds__(256) void cvt_kernel(
    const float* __restrict__ src, unsigned short* __restrict__ dst) {
  size_t i = ((size_t)blockIdx.x * 256 + threadIdx.x) * 8;
  float4 a = *reinterpret_cast<const float4*>(src + i);
  float4 b = *reinterpret_cast<const float4*>(src + i + 4);
  *reinterpret_cast<uint4*>(dst + i) = pack8(a, b);
}

// Persistent cooperative kernel, 1 custom grid barrier per step.
//   all waves  : stage h_{k-1} -> LDS (coherent reads)      [HLDS]
//   waves 0-7  : gates(k) from LDS (Whh reg-resident, 2 rows/wave);
//                logits(k-3); wave7/asub0: log-softmax(k-4)
//   waves 8-15 : attn partials(k-1) (cached ctx); waves 8-9: combine(k-2)
//   tid<128    : cell(k) -> coherent h write
template<bool BF16C, bool HLDS>
__global__ __launch_bounds__(NT, 4) void decoder_kernel(
    const float* __restrict__ ctxt, const float* __restrict__ gt,
    const float* __restrict__ Wih, const float* __restrict__ Whh,
    const float* __restrict__ Wout, const float* __restrict__ bout,
    float* __restrict__ ws, float* __restrict__ out) {
  const int blk = blockIdx.x;
  const int tid = threadIdx.x;
  const int lane = tid & 63;
  const int wv = tid >> 6;

  float* base  = ws;
  float* hbuf  = ws + HBUF_OFF;
  float* part  = ws + PART_OFF;
  float* ctxc  = ws + CTXC_OFF;
  float* lgbuf = ws + LG_OFF;
  unsigned* cnt = reinterpret_cast<unsigned*>(ws + CNT_OFF);
  const unsigned short* ctxb = reinterpret_cast<const unsigned short*>(ws + CTXB_OFF);

  extern __shared__ float smem[];
  float* h_lds = smem;                                  // [32*1024] if HLDS
  float* glds  = HLDS ? (smem + BATCH * HD) : smem;     // [512]

  const int ab   = blk >> 3;
  const int asub = blk & 7;

  // gate waves: preload time-invariant weights into registers (2 rows/wave)
  float4 Wr[2][4];
  float2 Wi2r[2];
  if (tid < 512) {
    const float4* Whh4 = reinterpret_cast<const float4*>(Whh);
    const float2* Wih2 = reinterpret_cast<const float2*>(Wih);
#pragma unroll
    for (int q = 0; q < 2; ++q) {
      const int rr = 2 * wv + q;
      const int grow = (rr >> 2) * HD + blk * 4 + (rr & 3);
#pragma unroll
      for (int t = 0; t < 4; ++t)
        Wr[q][t] = Whh4[(size_t)grow * 256 + lane + 64 * t];
      Wi2r[q] = Wih2[(size_t)grow * 576 + lane];
    }
  }
  float c_reg = 0.0f;

  const int aw    = wv - 8;
  const int chunk = asub * 8 + aw;
  const int pos0  = chunk * 16;

  for (int k = 0; k <= 131; ++k) {
    const float* hprev = hbuf + (size_t)((k + 3) & 3) * (BATCH * HD);
    if (HLDS && k <= LL) {
#pragma unroll
      for (int i = 0; i < 16; ++i) {
        unsigned long long v = cld8(hprev + 2 * (tid + 1024 * i));
        *reinterpret_cast<unsigned long long*>(h_lds + 2 * (tid + 1024 * i)) = v;
      }
    }
    __syncthreads();

    if (tid < 512) {
      // ---- gates(k): 2 rows/wave, 32 b, K split across lanes ----
      if (k <= LL - 1) {
        const float2* gt2 = reinterpret_cast<const float2*>(gt);
#pragma unroll 2
        for (int b = 0; b < BATCH; ++b) {
          float4 h0, h1, h2, h3;
          if constexpr (HLDS) {
            const float4* h4 = reinterpret_cast<const float4*>(h_lds + b * HD);
            h0 = h4[lane]; h1 = h4[lane + 64]; h2 = h4[lane + 128]; h3 = h4[lane + 192];
          } else {
            const float* hb = hprev + (size_t)b * HD;
            h0 = ldc4(hb + 4 * lane);         h1 = ldc4(hb + 4 * (lane + 64));
            h2 = ldc4(hb + 4 * (lane + 128)); h3 = ldc4(hb + 4 * (lane + 192));
          }
          float2 wd;
          if (k == 0) { wd.x = (lane == 0) ? 1.0f : 0.0f; wd.y = 0.0f; }
          else        { wd = gt2[((size_t)b * LL + (k - 1)) * 64 + lane]; }
          float4 d0 = make_float4(0,0,0,0), d1 = d0;
          fma4a(d0, h0, Wr[0][0]); fma4a(d0, h1, Wr[0][1]);
          fma4a(d0, h2, Wr[0][2]); fma4a(d0, h3, Wr[0][3]);
          fma4a(d1, h0, Wr[1][0]); fma4a(d1, h1, Wr[1][1]);
          fma4a(d1, h2, Wr[1][2]); fma4a(d1, h3, Wr[1][3]);
          float a0 = d0.x + d0.y + d0.z + d0.w;
          float a1 = d1.x + d1.y + d1.z + d1.w;
          a0 = fmaf(wd.x, Wi2r[0].x, a0); a0 = fmaf(wd.y, Wi2r[0].y, a0);
          a1 = fmaf(wd.x, Wi2r[1].x, a1); a1 = fmaf(wd.y, Wi2r[1].y, a1);
#pragma unroll
          for (int o = 32; o > 0; o >>= 1) {
            a0 += __shfl_xor(a0, o);
            a1 += __shfl_xor(a1, o);
          }
          if (lane == 0) {
            const int rr0 = 2 * wv, rr1 = 2 * wv + 1;
            glds[(rr0 >> 2) * 128 + (rr0 & 3) * 32 + b] =
                a0 + base[(size_t)b * GD + (rr0 >> 2) * HD + blk * 4 + (rr0 & 3)];
            glds[(rr1 >> 2) * 128 + (rr1 & 3) * 32 + b] =
                a1 + base[(size_t)b * GD + (rr1 >> 2) * HD + blk * 4 + (rr1 & 3)];
          }
        }
      }
      // ---- logits t3 = k-3 (2 e per gate wave) ----
      if (k >= 3 && k <= LL + 2) {
        const int t3 = k - 3;
        const float* hhp = hbuf + (size_t)(t3 & 3) * (BATCH * HD) + (size_t)ab * HD;
        const float* cxp = ctxc + (size_t)(t3 & 1) * (BATCH * HD) + (size_t)ab * HD;
        float4 hh[4], cx[4];
#pragma unroll
        for (int jj = 0; jj < 4; ++jj) {
          hh[jj] = ldc4(hhp + 4 * (lane + 64 * jj));
          cx[jj] = ldc4(cxp + 4 * (lane + 64 * jj));
        }
#pragma unroll
        for (int q = 0; q < 2; ++q) {
          const int e = asub * 16 + wv * 2 + q;
          const float4* wo = reinterpret_cast<const float4*>(Wout + (size_t)e * 2 * HD);
          float4 acc = make_float4(0,0,0,0);
#pragma unroll
          for (int jj = 0; jj < 4; ++jj) {
            fma4a(acc, hh[jj], wo[lane + 64 * jj]);
            fma4a(acc, cx[jj], wo[256 + lane + 64 * jj]);
          }
          float d = acc.x + acc.y + acc.z + acc.w;
#pragma unroll
          for (int o = 32; o > 0; o >>= 1) d += __shfl_xor(d, o);
          if (lane == 0)
            cstf(lgbuf + (size_t)(t3 & 1) * (BATCH * ED) + (size_t)ab * ED + e, d + bout[e]);
        }
      }
      // ---- log-softmax t4 = k-4 (wave 7 of asub==0 blocks) ----
      if (asub == 0 && wv == 7 && k >= 4) {
        const int t4 = k - 4;
        const float* lg = lgbuf + (size_t)(t4 & 1) * (BATCH * ED) + (size_t)ab * ED;
        float v0 = cldf(lg + lane), v1 = cldf(lg + lane + 64);
        float mx = fmaxf(v0, v1);
#pragma unroll
        for (int o = 32; o > 0; o >>= 1) mx = fmaxf(mx, __shfl_xor(mx, o));
        float sm = __expf(v0 - mx) + __expf(v1 - mx);
#pragma unroll
        for (int o = 32; o > 0; o >>= 1) sm += __shfl_xor(sm, o);
        float lse = mx + __logf(sm);
        float* op = out + ((size_t)ab * LL + t4) * ED;
        op[lane]      = v0 - lse;
        op[lane + 64] = v1 - lse;
      }
    } else {
      // ---- attention partials t1 = k-1 (16 positions/wave, cached ctx) ----
      if (k >= 1 && k <= LL) {
        const int t1 = k - 1;
        float4 hA0, hA1, hB0, hB1;
        if constexpr (HLDS) {
          const float4* h4 = reinterpret_cast<const float4*>(h_lds + ab * HD);
          hA0 = h4[2*lane]; hA1 = h4[2*lane+1];
          hB0 = h4[128+2*lane]; hB1 = h4[128+2*lane+1];
        } else {
          const float* hb = hprev + (size_t)ab * HD;
          hA0 = ldc4(hb + 8*lane);       hA1 = ldc4(hb + 8*lane + 4);
          hB0 = ldc4(hb + 512 + 8*lane); hB1 = ldc4(hb + 512 + 8*lane + 4);
        }
        float m = -3.0e38f, s = 0.0f;
        float4 aA0 = make_float4(0,0,0,0), aA1 = aA0, aB0 = aA0, aB1 = aA0;
        if constexpr (BF16C) {
          const uint4* cr4 = reinterpret_cast<const uint4*>(ctxb + ((size_t)ab*TENC + pos0)*HD);
          uint4 pa0 = cr4[lane],       pa1 = cr4[64 + lane];
          uint4 pb0 = cr4[128 + lane], pb1 = cr4[192 + lane];
          for (int p = 0; p < 16; ++p) {
            uint4 u0 = pa0, u1 = pa1;
            pa0 = pb0; pa1 = pb1;
            if (p < 14) { pb0 = cr4[(p+2)*128 + lane]; pb1 = cr4[(p+2)*128 + 64 + lane]; }
            float4 cA0 = make_float4(bflo(u0.x), bfhi(u0.x), bflo(u0.y), bfhi(u0.y));
            float4 cA1 = make_float4(bflo(u0.z), bfhi(u0.z), bflo(u0.w), bfhi(u0.w));
            float4 cB0 = make_float4(bflo(u1.x), bfhi(u1.x), bflo(u1.y), bfhi(u1.y));
            float4 cB1 = make_float4(bflo(u1.z), bfhi(u1.z), bflo(u1.w), bfhi(u1.w));
            float4 dv = make_float4(0,0,0,0);
            fma4a(dv, cA0, hA0); fma4a(dv, cA1, hA1);
            fma4a(dv, cB0, hB0); fma4a(dv, cB1, hB1);
            float d = dv.x + dv.y + dv.z + dv.w;
#pragma unroll
            for (int o = 32; o > 0; o >>= 1) d += __shfl_xor(d, o);
            float mn = fmaxf(m, d);
            if (mn > m) {            // wave-uniform
              float sc = __expf(m - mn);
              s *= sc; mul4(aA0, sc); mul4(aA1, sc); mul4(aB0, sc); mul4(aB1, sc);
              m = mn;
            }
            float pw = __expf(d - m);
            s += pw;
            fma4(aA0, pw, cA0); fma4(aA1, pw, cA1);
            fma4(aB0, pw, cB0); fma4(aB1, pw, cB1);
          }
        } else {
          const float4* cf4 = reinterpret_cast<const float4*>(ctxt + ((size_t)ab*TENC + pos0)*HD);
          float4 f0 = cf4[2*lane], f1 = cf4[2*lane+1];
          float4 f2 = cf4[128+2*lane], f3 = cf4[128+2*lane+1];
          for (int p = 0; p < 16; ++p) {
            float4 cA0 = f0, cA1 = f1, cB0 = f2, cB1 = f3;
            if (p < 15) {
              f0 = cf4[(p+1)*256 + 2*lane];       f1 = cf4[(p+1)*256 + 2*lane+1];
              f2 = cf4[(p+1)*256 + 128 + 2*lane]; f3 = cf4[(p+1)*256 + 128 + 2*lane+1];
            }
            float4 dv = make_float4(0,0,0,0);
            fma4a(dv, cA0, hA0); fma4a(dv, cA1, hA1);
            fma4a(dv, cB0, hB0); fma4a(dv, cB1, hB1);
            float d = dv.x + dv.y + dv.z + dv.w;
#pragma unroll
            for (int o = 32; o > 0; o >>= 1) d += __shfl_xor(d, o);
            float mn = fmaxf(m, d);
            if (mn > m) {
              float sc = __expf(m - mn);
              s *= sc; mul4(aA0, sc); mul4(aA1, sc); mul4(aB0, sc); mul4(aB1, sc);
              m = mn;
            }
            float pw = __expf(d - m);
            s += pw;
            fma4(aA0, pw, cA0); fma4(aA1, pw, cA1);
            fma4(aB0, pw, cB0); fma4(aB1, pw, cB1);
          }
        }
        float* pb = part + ((size_t)(((t1 & 1)) * BATCH + ab) * NCHUNK + chunk) * PSTR;
        unsigned long long* pu = reinterpret_cast<unsigned long long*>(pb);
        uint4 rA = pack8(aA0, aA1), rB = pack8(aB0, aB1);
        cst8(pu + 2*lane,           ((unsigned long long)rA.y << 32) | rA.x);
        cst8(pu + 2*lane + 1,       ((unsigned long long)rA.w << 32) | rA.z);
        cst8(pu + 128 + 2*lane,     ((unsigned long long)rB.y << 32) | rB.x);
        cst8(pu + 128 + 2*lane + 1, ((unsigned long long)rB.w << 32) | rB.z);
        if (lane == 0) cst8(pu + 256, f2u(m, s));
      }
      // ---- combine t2 = k-2 (waves 8-9: 128 elements/block) ----
      if (aw < 2 && k >= 2 && k <= LL + 1) {
        const int tid2 = tid - 512;
        const int t2 = k - 2;
        const int e = asub * 128 + tid2;
        const float* pb0 = part + (size_t)((t2 & 1) * BATCH + ab) * NCHUNK * PSTR;
        float mc = cldf(pb0 + (size_t)lane * PSTR + 512);
        float sc = cldf(pb0 + (size_t)lane * PSTR + 513);
        float M = mc;
#pragma unroll
        for (int o = 32; o > 0; o >>= 1) M = fmaxf(M, __shfl_xor(M, o));
        float wl = __expf(mc - M);
        float S = wl * sc;
#pragma unroll
        for (int o = 32; o > 0; o >>= 1) S += __shfl_xor(S, o);
        const unsigned short* pu0 = reinterpret_cast<const unsigned short*>(pb0);
        float acc = 0.0f;
#pragma unroll 8
        for (int c = 0; c < NCHUNK; ++c) {
          float w = __shfl(wl, c);
          unsigned u = cld4(pu0 + (size_t)c * (PSTR * 2) + (e & ~1));
          float v = (e & 1) ? bfhi(u) : bflo(u);
          acc = fmaf(w, v, acc);
        }
        cstf(ctxc + (size_t)(t2 & 1) * (BATCH * HD) + (size_t)ab * HD + e,
             acc * __builtin_amdgcn_rcpf(S));
      }
    }
    __syncthreads();
    // ---- cell(k): 128 threads, coherent h write ----
    if (tid < 128 && k <= LL - 1) {
      const int cb = tid & 31, cw = tid >> 5;
      float ig = sigf(glds[cw * 32 + cb]);
      float fg = sigf(glds[128 + cw * 32 + cb]);
      float gg = tanhf_fast(glds[256 + cw * 32 + cb]);
      float og = sigf(glds[384 + cw * 32 + cb]);
      c_reg = fg * c_reg + ig * gg;
      cstf(hbuf + (size_t)(k & 3) * (BATCH * HD) + (size_t)cb * HD + blk * 4 + cw,
           og * tanhf_fast(c_reg));
    }
    if (k < 131) gbar(cnt, (unsigned)((k + 1) * NB));
  }
}

extern "C" void kernel_launch(void* const* d_in, const int* in_sizes, int n_in,
                              void* d_out, int out_size, void* d_ws, size_t ws_size,
                              hipStream_t stream) {
  (void)in_sizes; (void)n_in; (void)out_size;
  const float* ctxt = (const float*)d_in[0];
  const float* gt   = (const float*)d_in[1];
  const float* Wih  = (const float*)d_in[2];
  const float* Whh  = (const float*)d_in[3];
  const float* bih  = (const float*)d_in[4];
  const float* bhh  = (const float*)d_in[5];
  const float* Wout = (const float*)d_in[6];
  const float* bout = (const float*)d_in[7];
  float* out = (float*)d_out;
  float* ws  = (float*)d_ws;

  const bool bf16c = (ws_size / sizeof(float)) >= WS_NEED_BF16;

  hipMemsetAsync(ws + HBUF_OFF, 0, (size_t)4 * BATCH * HD * sizeof(float), stream);
  hipMemsetAsync(ws + CNT_OFF, 0, 256, stream);

  base_kernel<<<(BATCH * GD) / 256, 256, 0, stream>>>(ctxt, Wih, bih, bhh, ws);
  if (bf16c) {
    cvt_kernel<<<(BATCH * TENC * HD / 8) / 256, 256, 0, stream>>>(
        ctxt, reinterpret_cast<unsigned short*>(ws + CTXB_OFF));
  }

  void* args[] = { (void*)&ctxt, (void*)&gt, (void*)&Wih, (void*)&Whh,
                   (void*)&Wout, (void*)&bout, (void*)&ws, (void*)&out };

  int smem = (BATCH * HD + 512) * (int)sizeof(float);   // 133120 B
  const void* kf = bf16c ? (const void*)&decoder_kernel<true, true>
                         : (const void*)&decoder_kernel<false, true>;
  if (hipFuncSetAttribute(kf, hipFuncAttributeMaxDynamicSharedMemorySize, smem)
      != hipSuccess) {
    // fallback: no LDS h-staging (coherent reads straight from ws)
    smem = 512 * (int)sizeof(float);
    kf = bf16c ? (const void*)&decoder_kernel<true, false>
               : (const void*)&decoder_kernel<false, false>;
  }
  hipLaunchCooperativeKernel(kf, dim3(NB), dim3(NT), args, smem, stream);
}